// Round 1
// 140.863 us; speedup vs baseline: 1.0241x; 1.0241x over previous
//
#include <hip/hip_runtime.h>

#define B_N 16
#define S_LEN 2048
#define D_DIM 128
#define TK 32
#define NTH 32            // tiles per key-half (2 groups x 32 x 32 keys = 2048)

typedef __attribute__((ext_vector_type(16))) float f32x16;
typedef __attribute__((ext_vector_type(8)))  short short8;
typedef __attribute__((ext_vector_type(4)))  int   i32x4;
typedef const __attribute__((address_space(1))) void* gp1;
typedef __attribute__((address_space(3))) void* sp3;
// DMA: wave-uniform LDS base, HW lands lane L's 16B at base + L*16
#define GLL(g, l) __builtin_amdgcn_global_load_lds((gp1)(const void*)(g), (sp3)(void*)(l), 16, 0, 0)

static __device__ __forceinline__ unsigned short f2bf(float f) {
  unsigned u = __builtin_bit_cast(unsigned, f);
  return (unsigned short)((u + 0x7fffu + ((u >> 16) & 1u)) >> 16);  // RNE
}

// ---------------- prepass: K -> bf16 row-major; V -> bf16 transposed [b][d][s] ----------------
__global__ __launch_bounds__(256)
void prep_kernel(const float* __restrict__ K, const float* __restrict__ V,
                 unsigned short* __restrict__ Kb, unsigned short* __restrict__ VT) {
  __shared__ unsigned short lds[64 * 66];
  int bx = blockIdx.x;
  int t  = threadIdx.x;
  if (bx < 4096) {
    // K convert: 4 elems/thread, fully coalesced
    size_t i = ((size_t)bx * 256 + t) * 4;
    float4 v = *(const float4*)(K + i);
    unsigned lo = (unsigned)f2bf(v.x) | ((unsigned)f2bf(v.y) << 16);
    unsigned hi = (unsigned)f2bf(v.z) | ((unsigned)f2bf(v.w) << 16);
    *(uint2*)(Kb + i) = make_uint2(lo, hi);
  } else {
    // V transpose+convert: 64(s) x 64(d) tile via LDS, float4 both sides
    int bi = bx - 4096;                 // 1024 = 16 b x 32 st x 2 dt
    int b  = bi & 15;
    int st = (bi >> 4) & 31;
    int dt = bi >> 9;
    const float* Vb = V + ((size_t)b * S_LEN + st * 64) * D_DIM + dt * 64;
    unsigned short* VTb = VT + ((size_t)b * D_DIM + dt * 64) * S_LEN + st * 64;
#pragma unroll
    for (int rep = 0; rep < 4; ++rep) {
      int idx = rep * 256 + t;
      int i  = idx >> 4;                // s-local 0..63
      int j4 = (idx & 15) * 4;          // d-local
      float4 v = *(const float4*)(Vb + (size_t)i * D_DIM + j4);
      unsigned lo = (unsigned)f2bf(v.x) | ((unsigned)f2bf(v.y) << 16);
      unsigned hi = (unsigned)f2bf(v.z) | ((unsigned)f2bf(v.w) << 16);
      *(uint2*)&lds[i * 66 + j4] = make_uint2(lo, hi);
    }
    __syncthreads();
#pragma unroll
    for (int rep = 0; rep < 4; ++rep) {
      int idx = rep * 256 + t;
      int dd = idx >> 4;                // d-local 0..63
      int s4 = (idx & 15) * 4;          // s-local
      unsigned short e0 = lds[(s4 + 0) * 66 + dd];
      unsigned short e1 = lds[(s4 + 1) * 66 + dd];
      unsigned short e2 = lds[(s4 + 2) * 66 + dd];
      unsigned short e3 = lds[(s4 + 3) * 66 + dd];
      *(uint2*)(VTb + (size_t)dd * S_LEN + s4) =
          make_uint2((unsigned)e0 | ((unsigned)e1 << 16),
                     (unsigned)e2 | ((unsigned)e3 << 16));
    }
  }
}

// ---------------- main attention kernel: 512 thr, split-K across wave groups ----------------
// T12: swapped QK^T (mfma(K,Q)) -> P is lane-local per q-row; P->A-frag rebuilt fully
// in-register via v_cvt_pk_bf16_f32 + v_permlane32_swap_b32. No P LDS round-trip.
__global__ __launch_bounds__(512, 2)
void attn_kernel(const float* __restrict__ Q, const unsigned short* __restrict__ Kb,
                 const unsigned short* __restrict__ VT, float* __restrict__ O) {
  // layout: [0,32768) kbuf[g][buf][4096sh] | [32768,65536) vbuf
  // merge overlay (post-loop): per-w4 stride 16640 B = O 16384B + l1 128B + l0 128B
  __shared__ __align__(16) char smem[66560];

  const int tid  = threadIdx.x;
  const int wave = tid >> 6;
  const int g    = wave >> 2;           // key-half group
  const int w4   = wave & 3;            // q-row-group within block
  const int lane = tid & 63;
  const int l32  = lane & 31;
  const int half = lane >> 5;

  // XCD swizzle: all 16 q-blocks of one batch land on the same XCD (K/V L2 residency)
  const int i     = blockIdx.x;
  const int b     = (i & 7) * 2 + ((i >> 3) & 1);
  const int qtile = i >> 4;
  const int qbase = qtile * 128 + w4 * 32;

  const float* Qb = Q + (size_t)b * S_LEN * D_DIM;
  const unsigned short* Kbb = Kb + (size_t)b * S_LEN * D_DIM;
  const unsigned short* VTb = VT + (size_t)b * D_DIM * S_LEN;

  unsigned short* kb0 = (unsigned short*)smem + (size_t)g * 2 * 4096;
  unsigned short* vb0 = (unsigned short*)(smem + 32768) + (size_t)g * 2 * 4096;

  // ---- issue DMA for this group's tile 0 (buffer 0) ----
  {
    const int T0 = g * NTH;
#pragma unroll
    for (int cc = 0; cc < 2; ++cc) {
      int c = w4 * 2 + cc;
      int rl = 4 * c + (lane >> 4);
      int lbk = (lane & 15) ^ (rl & 15);
      GLL(Kbb + (size_t)(T0 * TK + rl) * D_DIM + lbk * 8, kb0 + c * 512);
      int dv = 16 * c + (lane >> 2);
      int lbv = (lane & 3) ^ ((dv >> 1) & 3);
      GLL(VTb + (size_t)dv * S_LEN + T0 * TK + lbv * 8, vb0 + c * 512);
    }
  }

  // ---- Q B-frags (32x32x16: B[n=lane&31][k=half*8+j]), fp32->bf16 once ----
  short8 qa[8];
  {
    const float* qp = Qb + (size_t)(qbase + l32) * D_DIM + half * 8;
#pragma unroll
    for (int ks = 0; ks < 8; ++ks) {
      float4 a0 = *(const float4*)(qp + ks * 16);
      float4 a1 = *(const float4*)(qp + ks * 16 + 4);
      short8 f;
      f[0] = (short)f2bf(a0.x); f[1] = (short)f2bf(a0.y);
      f[2] = (short)f2bf(a0.z); f[3] = (short)f2bf(a0.w);
      f[4] = (short)f2bf(a1.x); f[5] = (short)f2bf(a1.y);
      f[6] = (short)f2bf(a1.z); f[7] = (short)f2bf(a1.w);
      qa[ks] = f;
    }
  }

  const f32x16 zf16 = {0.f,0.f,0.f,0.f,0.f,0.f,0.f,0.f,0.f,0.f,0.f,0.f,0.f,0.f,0.f,0.f};
  f32x16 oacc[4];
  float lsum = 0.f;
#pragma unroll
  for (int dt = 0; dt < 4; ++dt) oacc[dt] = zf16;

  const float SC = 0.08838834764831845f * 1.4426950408889634f; // 1/sqrt(128)*log2(e)

  for (int t = 0; t < NTH; ++t) {
    __syncthreads();  // drains DMA(t) for both groups; frees buf (t+1)&1
    const int cb = t & 1;
    const unsigned short* kbc = kb0 + cb * 4096;
    const unsigned short* vbc = vb0 + cb * 4096;

    if (t + 1 < NTH) {  // DMA(t+1) flies during compute(t)
      const int nb = cb ^ 1;
      const int T = g * NTH + t + 1;
#pragma unroll
      for (int cc = 0; cc < 2; ++cc) {
        int c = w4 * 2 + cc;
        int rl = 4 * c + (lane >> 4);
        int lbk = (lane & 15) ^ (rl & 15);
        GLL(Kbb + (size_t)(T * TK + rl) * D_DIM + lbk * 8, kb0 + nb * 4096 + c * 512);
        int dv = 16 * c + (lane >> 2);
        int lbv = (lane & 3) ^ ((dv >> 1) & 3);
        GLL(VTb + (size_t)dv * S_LEN + T * TK + lbv * 8, vb0 + nb * 4096 + c * 512);
      }
    }

    // ---- S^T = K Q^T (32 keys x 32 q-rows), K-dim 128 = 8 MFMAs ----
    // C[m=key][n=qrow]: lane holds qrow = l32, keys = (reg&3)+8*(reg>>2)+4*half
    f32x16 sacc = zf16;
#pragma unroll
    for (int ks = 0; ks < 8; ++ks) {
      int pk = (ks * 2 + half) ^ (l32 & 15);
      short8 kf = *(const short8*)&kbc[l32 * D_DIM + pk * 8];
      sacc = __builtin_amdgcn_mfma_f32_32x32x16_bf16(kf, qa[ks], sacc, 0, 0, 0);
    }

    // ---- max-free softmax, fully in-register ----
    float p[16];
#pragma unroll
    for (int reg = 0; reg < 16; ++reg) {
      p[reg] = exp2f(sacc[reg] * SC);
      lsum += p[reg];
    }

    // pack pairs: dw[i] = {bf16(p[2i]) lo, bf16(p[2i+1]) hi}
    // dw0/1: keys 4h+0..3 | dw2/3: keys 8+4h+0..3 | dw4/5: keys 16+4h.. | dw6/7: keys 24+4h..
    int dw[8];
#pragma unroll
    for (int i2 = 0; i2 < 8; ++i2)
      asm("v_cvt_pk_bf16_f32 %0, %1, %2"
          : "=v"(dw[i2]) : "v"(p[2 * i2]), "v"(p[2 * i2 + 1]));
    // permlane32_swap: vdst[32:63] <-> vsrc[0:31]. Builds A-frag words:
    // ks2=0 needs keys h*8+0..7 ; ks2=1 needs keys 16+h*8+0..7
    asm("v_permlane32_swap_b32 %0, %1" : "+v"(dw[0]), "+v"(dw[2]));  // -> w0, w2 of pf0
    asm("v_permlane32_swap_b32 %0, %1" : "+v"(dw[1]), "+v"(dw[3]));  // -> w1, w3 of pf0
    asm("v_permlane32_swap_b32 %0, %1" : "+v"(dw[4]), "+v"(dw[6]));  // -> w0, w2 of pf1
    asm("v_permlane32_swap_b32 %0, %1" : "+v"(dw[5]), "+v"(dw[7]));  // -> w1, w3 of pf1
    i32x4 f0 = {dw[0], dw[1], dw[2], dw[3]};
    i32x4 f1 = {dw[4], dw[5], dw[6], dw[7]};
    short8 pf[2];
    pf[0] = __builtin_bit_cast(short8, f0);
    pf[1] = __builtin_bit_cast(short8, f1);

    // ---- O += P V (B from transposed V tile) ----
#pragma unroll
    for (int ks2 = 0; ks2 < 2; ++ks2) {
#pragma unroll
      for (int dt = 0; dt < 4; ++dt) {
        int dv = dt * 32 + l32;
        int pv = (ks2 * 2 + half) ^ ((dv >> 1) & 3);
        short8 vf = *(const short8*)&vbc[dv * TK + pv * 8];
        oacc[dt] = __builtin_amdgcn_mfma_f32_32x32x16_bf16(pf[ks2], vf, oacc[dt], 0, 0, 0);
      }
    }
  }

  // ---- combine halves: lane l32 then holds full key-half row sum for qrow = l32 ----
  lsum += __shfl_xor(lsum, 32);

  // ---- split-K merge: group 1 -> LDS, group 0 adds, normalizes, stores ----
  __syncthreads();  // all tile reads done; safe to overlay merge region
  float* mo  = (float*)(smem + w4 * 16640);
  float* ml1 = (float*)(smem + w4 * 16640 + 16384);        // group-1 row sums (32 f)
  float* ml0 = ml1 + 32;                                   // group-0 row sums (32 f)
  if (g == 1) {
#pragma unroll
    for (int reg = 0; reg < 16; ++reg) {
      int row = (reg & 3) + 8 * (reg >> 2) + 4 * half;
#pragma unroll
      for (int dt = 0; dt < 4; ++dt)
        mo[row * 128 + dt * 32 + l32] = oacc[dt][reg];
    }
    if (half == 0) ml1[l32] = lsum;
  } else {
    if (half == 0) ml0[l32] = lsum;
  }
  __syncthreads();
  if (g == 0) {
    float* Ob = O + (size_t)b * S_LEN * D_DIM;
#pragma unroll
    for (int reg = 0; reg < 16; ++reg) {
      int row = (reg & 3) + 8 * (reg >> 2) + 4 * half;
      float linv = 1.f / (ml0[row] + ml1[row]);
#pragma unroll
      for (int dt = 0; dt < 4; ++dt)
        Ob[(size_t)(qbase + row) * D_DIM + dt * 32 + l32] =
            (oacc[dt][reg] + mo[row * 128 + dt * 32 + l32]) * linv;
    }
  }
}

extern "C" void kernel_launch(void* const* d_in, const int* in_sizes, int n_in,
                              void* d_out, int out_size, void* d_ws, size_t ws_size,
                              hipStream_t stream) {
  const float* Q = (const float*)d_in[0];
  const float* K = (const float*)d_in[1];
  const float* V = (const float*)d_in[2];
  float* O = (float*)d_out;
  unsigned short* Kb = (unsigned short*)d_ws;                       // 8.4 MB
  unsigned short* VT = Kb + (size_t)B_N * S_LEN * D_DIM;            // 8.4 MB
  prep_kernel<<<dim3(4096 + 1024), dim3(256), 0, stream>>>(K, V, Kb, VT);
  attn_kernel<<<dim3(256), dim3(512), 0, stream>>>(Q, Kb, VT, O);
}

// Round 2
// 137.338 us; speedup vs baseline: 1.0504x; 1.0257x over previous
//
#include <hip/hip_runtime.h>

#define B_N 16
#define S_LEN 2048
#define D_DIM 128
#define TK 32
#define NTH 32            // tiles per key-half (2 groups x 32 x 32 keys = 2048)

typedef __attribute__((ext_vector_type(16))) float f32x16;
typedef __attribute__((ext_vector_type(8)))  short short8;
typedef __attribute__((ext_vector_type(4)))  int   i32x4;
typedef const __attribute__((address_space(1))) void* gp1;
typedef __attribute__((address_space(3))) void* sp3;
// DMA: wave-uniform LDS base, HW lands lane L's 16B at base + L*16
#define GLL(g, l) __builtin_amdgcn_global_load_lds((gp1)(const void*)(g), (sp3)(void*)(l), 16, 0, 0)

static __device__ __forceinline__ unsigned short f2bf(float f) {
  unsigned u = __builtin_bit_cast(unsigned, f);
  return (unsigned short)((u + 0x7fffu + ((u >> 16) & 1u)) >> 16);  // RNE
}

// ---------------- prepass: K -> bf16 row-major; V -> bf16 transposed [b][d][s] ----------------
__global__ __launch_bounds__(256)
void prep_kernel(const float* __restrict__ K, const float* __restrict__ V,
                 unsigned short* __restrict__ Kb, unsigned short* __restrict__ VT) {
  __shared__ unsigned short lds[64 * 66];
  int bx = blockIdx.x;
  int t  = threadIdx.x;
  if (bx < 4096) {
    // K convert: 4 elems/thread, fully coalesced
    size_t i = ((size_t)bx * 256 + t) * 4;
    float4 v = *(const float4*)(K + i);
    unsigned lo = (unsigned)f2bf(v.x) | ((unsigned)f2bf(v.y) << 16);
    unsigned hi = (unsigned)f2bf(v.z) | ((unsigned)f2bf(v.w) << 16);
    *(uint2*)(Kb + i) = make_uint2(lo, hi);
  } else {
    // V transpose+convert: 64(s) x 64(d) tile via LDS, float4 both sides
    int bi = bx - 4096;                 // 1024 = 16 b x 32 st x 2 dt
    int b  = bi & 15;
    int st = (bi >> 4) & 31;
    int dt = bi >> 9;
    const float* Vb = V + ((size_t)b * S_LEN + st * 64) * D_DIM + dt * 64;
    unsigned short* VTb = VT + ((size_t)b * D_DIM + dt * 64) * S_LEN + st * 64;
#pragma unroll
    for (int rep = 0; rep < 4; ++rep) {
      int idx = rep * 256 + t;
      int i  = idx >> 4;                // s-local 0..63
      int j4 = (idx & 15) * 4;          // d-local
      float4 v = *(const float4*)(Vb + (size_t)i * D_DIM + j4);
      unsigned lo = (unsigned)f2bf(v.x) | ((unsigned)f2bf(v.y) << 16);
      unsigned hi = (unsigned)f2bf(v.z) | ((unsigned)f2bf(v.w) << 16);
      *(uint2*)&lds[i * 66 + j4] = make_uint2(lo, hi);
    }
    __syncthreads();
#pragma unroll
    for (int rep = 0; rep < 4; ++rep) {
      int idx = rep * 256 + t;
      int dd = idx >> 4;                // d-local 0..63
      int s4 = (idx & 15) * 4;          // s-local
      unsigned short e0 = lds[(s4 + 0) * 66 + dd];
      unsigned short e1 = lds[(s4 + 1) * 66 + dd];
      unsigned short e2 = lds[(s4 + 2) * 66 + dd];
      unsigned short e3 = lds[(s4 + 3) * 66 + dd];
      *(uint2*)(VTb + (size_t)dd * S_LEN + s4) =
          make_uint2((unsigned)e0 | ((unsigned)e1 << 16),
                     (unsigned)e2 | ((unsigned)e3 << 16));
    }
  }
}

// ---------------- main attention kernel: 512 thr, split-K across wave groups ----------------
// T12: swapped QK^T (mfma(K,Q)) -> P lane-local, rebuilt via cvt_pk_bf16 + permlane32_swap.
// T4: triple-buffered LDS + counted s_waitcnt vmcnt(4) + raw s_barrier -> DMA never drains
// in the main loop; each global_load_lds gets ~2 tile-iterations to land.
__global__ __launch_bounds__(512, 2)
void attn_kernel(const float* __restrict__ Q, const unsigned short* __restrict__ Kb,
                 const unsigned short* __restrict__ VT, float* __restrict__ O) {
  // layout: [0,49152) kbuf[g][3][4096sh] | [49152,98304) vbuf[g][3][4096sh]
  // merge overlay (post-loop): per-w4 stride 16640 B = O 16384B + l1 128B + l0 128B
  __shared__ __align__(16) char smem[98304];

  const int tid  = threadIdx.x;
  const int wave = tid >> 6;
  const int g    = wave >> 2;           // key-half group
  const int w4   = wave & 3;            // q-row-group within block
  const int lane = tid & 63;
  const int l32  = lane & 31;
  const int half = lane >> 5;

  // XCD swizzle: all 16 q-blocks of one batch land on the same XCD (K/V L2 residency)
  const int i     = blockIdx.x;
  const int b     = (i & 7) * 2 + ((i >> 3) & 1);
  const int qtile = i >> 4;
  const int qbase = qtile * 128 + w4 * 32;

  const float* Qb = Q + (size_t)b * S_LEN * D_DIM;
  const unsigned short* Kbb = Kb + (size_t)b * S_LEN * D_DIM;
  const unsigned short* VTb = VT + (size_t)b * D_DIM * S_LEN;

  unsigned short* kb0 = (unsigned short*)smem + (size_t)g * 3 * 4096;
  unsigned short* vb0 = (unsigned short*)(smem + 49152) + (size_t)g * 3 * 4096;

  // per-wave DMA of one tile: 4 GLLs (2 K chunks + 2 V chunks)
  // in-flight accounting: exactly 4 vmcnt items per prefetched tile per wave
#define ISSUE_TILE(tt, buf)                                                        \
  {                                                                                \
    const int T_ = g * NTH + (tt);                                                 \
    _Pragma("unroll")                                                              \
    for (int cc = 0; cc < 2; ++cc) {                                               \
      int c = w4 * 2 + cc;                                                         \
      int rl = 4 * c + (lane >> 4);                                                \
      int lbk = (lane & 15) ^ (rl & 15);                                           \
      GLL(Kbb + (size_t)(T_ * TK + rl) * D_DIM + lbk * 8, kb0 + (buf) * 4096 + c * 512); \
      int dv = 16 * c + (lane >> 2);                                               \
      int lbv = (lane & 3) ^ ((dv >> 1) & 3);                                      \
      GLL(VTb + (size_t)dv * S_LEN + T_ * TK + lbv * 8, vb0 + (buf) * 4096 + c * 512);   \
    }                                                                              \
  }

  // ---- prologue: tiles 0 and 1 in flight ----
  ISSUE_TILE(0, 0)
  ISSUE_TILE(1, 1)

  // ---- Q B-frags (32x32x16: B[n=lane&31][k=half*8+j]), fp32->bf16 once ----
  short8 qa[8];
  {
    const float* qp = Qb + (size_t)(qbase + l32) * D_DIM + half * 8;
#pragma unroll
    for (int ks = 0; ks < 8; ++ks) {
      float4 a0 = *(const float4*)(qp + ks * 16);
      float4 a1 = *(const float4*)(qp + ks * 16 + 4);
      short8 f;
      f[0] = (short)f2bf(a0.x); f[1] = (short)f2bf(a0.y);
      f[2] = (short)f2bf(a0.z); f[3] = (short)f2bf(a0.w);
      f[4] = (short)f2bf(a1.x); f[5] = (short)f2bf(a1.y);
      f[6] = (short)f2bf(a1.z); f[7] = (short)f2bf(a1.w);
      qa[ks] = f;
    }
  }

  const f32x16 zf16 = {0.f,0.f,0.f,0.f,0.f,0.f,0.f,0.f,0.f,0.f,0.f,0.f,0.f,0.f,0.f,0.f};
  f32x16 oacc[4];
  float lsum = 0.f;
#pragma unroll
  for (int dt = 0; dt < 4; ++dt) oacc[dt] = zf16;

  const float SC = 0.08838834764831845f * 1.4426950408889634f; // 1/sqrt(128)*log2(e)

  int cur = 0;   // t % 3
  int pre = 2;   // (t+2) % 3
  for (int t = 0; t < NTH; ++t) {
    // wait own tile-t loads (leave tile-(t+1)'s 4 in flight), then cross-wave barrier:
    // after barrier, ALL waves' tile-t chunks have landed.
    if (t + 1 < NTH) {
      asm volatile("s_waitcnt vmcnt(4)" ::: "memory");
    } else {
      asm volatile("s_waitcnt vmcnt(0)" ::: "memory");
    }
    __builtin_amdgcn_s_barrier();

    // prefetch tile t+2 into the buffer last read at iter t-1 (reads there were all
    // consumed by MFMAs before any wave reached this barrier)
    if (t + 2 < NTH) ISSUE_TILE(t + 2, pre)

    const unsigned short* kbc = kb0 + cur * 4096;
    const unsigned short* vbc = vb0 + cur * 4096;

    // ---- S^T = K Q^T (32 keys x 32 q-rows), K-dim 128 = 8 MFMAs ----
    // C[m=key][n=qrow]: lane holds qrow = l32, keys = (reg&3)+8*(reg>>2)+4*half
    f32x16 sacc = zf16;
#pragma unroll
    for (int ks = 0; ks < 8; ++ks) {
      int pk = (ks * 2 + half) ^ (l32 & 15);
      short8 kf = *(const short8*)&kbc[l32 * D_DIM + pk * 8];
      sacc = __builtin_amdgcn_mfma_f32_32x32x16_bf16(kf, qa[ks], sacc, 0, 0, 0);
    }

    // ---- max-free softmax, fully in-register ----
    float p[16];
#pragma unroll
    for (int reg = 0; reg < 16; ++reg) {
      p[reg] = exp2f(sacc[reg] * SC);
      lsum += p[reg];
    }

    // pack pairs: dw[i] = {bf16(p[2i]) lo, bf16(p[2i+1]) hi}
    int dw[8];
#pragma unroll
    for (int i2 = 0; i2 < 8; ++i2)
      asm("v_cvt_pk_bf16_f32 %0, %1, %2"
          : "=v"(dw[i2]) : "v"(p[2 * i2]), "v"(p[2 * i2 + 1]));
    // permlane32_swap: vdst[32:63] <-> vsrc[0:31]. Builds A-frag words:
    // ks2=0 needs keys h*8+0..7 ; ks2=1 needs keys 16+h*8+0..7
    asm("v_permlane32_swap_b32 %0, %1" : "+v"(dw[0]), "+v"(dw[2]));
    asm("v_permlane32_swap_b32 %0, %1" : "+v"(dw[1]), "+v"(dw[3]));
    asm("v_permlane32_swap_b32 %0, %1" : "+v"(dw[4]), "+v"(dw[6]));
    asm("v_permlane32_swap_b32 %0, %1" : "+v"(dw[5]), "+v"(dw[7]));
    i32x4 f0 = {dw[0], dw[1], dw[2], dw[3]};
    i32x4 f1 = {dw[4], dw[5], dw[6], dw[7]};
    short8 pf[2];
    pf[0] = __builtin_bit_cast(short8, f0);
    pf[1] = __builtin_bit_cast(short8, f1);

    // ---- O += P V (B from transposed V tile) ----
#pragma unroll
    for (int ks2 = 0; ks2 < 2; ++ks2) {
#pragma unroll
      for (int dt = 0; dt < 4; ++dt) {
        int dv = dt * 32 + l32;
        int pv = (ks2 * 2 + half) ^ ((dv >> 1) & 3);
        short8 vf = *(const short8*)&vbc[dv * TK + pv * 8];
        oacc[dt] = __builtin_amdgcn_mfma_f32_32x32x16_bf16(pf[ks2], vf, oacc[dt], 0, 0, 0);
      }
    }

    cur = (cur == 2) ? 0 : cur + 1;
    pre = (pre == 2) ? 0 : pre + 1;
  }
#undef ISSUE_TILE

  // ---- combine halves: lane l32 then holds full key-half row sum for qrow = l32 ----
  lsum += __shfl_xor(lsum, 32);

  // ---- split-K merge: group 1 -> LDS, group 0 adds, normalizes, stores ----
  __syncthreads();  // full drain; safe to overlay merge region onto k/v buffers
  float* mo  = (float*)(smem + w4 * 16640);
  float* ml1 = (float*)(smem + w4 * 16640 + 16384);        // group-1 row sums (32 f)
  float* ml0 = ml1 + 32;                                   // group-0 row sums (32 f)
  if (g == 1) {
#pragma unroll
    for (int reg = 0; reg < 16; ++reg) {
      int row = (reg & 3) + 8 * (reg >> 2) + 4 * half;
#pragma unroll
      for (int dt = 0; dt < 4; ++dt)
        mo[row * 128 + dt * 32 + l32] = oacc[dt][reg];
    }
    if (half == 0) ml1[l32] = lsum;
  } else {
    if (half == 0) ml0[l32] = lsum;
  }
  __syncthreads();
  if (g == 0) {
    float* Ob = O + (size_t)b * S_LEN * D_DIM;
#pragma unroll
    for (int reg = 0; reg < 16; ++reg) {
      int row = (reg & 3) + 8 * (reg >> 2) + 4 * half;
      float linv = 1.f / (ml0[row] + ml1[row]);
#pragma unroll
      for (int dt = 0; dt < 4; ++dt)
        Ob[(size_t)(qbase + row) * D_DIM + dt * 32 + l32] =
            (oacc[dt][reg] + mo[row * 128 + dt * 32 + l32]) * linv;
    }
  }
}

extern "C" void kernel_launch(void* const* d_in, const int* in_sizes, int n_in,
                              void* d_out, int out_size, void* d_ws, size_t ws_size,
                              hipStream_t stream) {
  const float* Q = (const float*)d_in[0];
  const float* K = (const float*)d_in[1];
  const float* V = (const float*)d_in[2];
  float* O = (float*)d_out;
  unsigned short* Kb = (unsigned short*)d_ws;                       // 8.4 MB
  unsigned short* VT = Kb + (size_t)B_N * S_LEN * D_DIM;            // 8.4 MB
  prep_kernel<<<dim3(4096 + 1024), dim3(256), 0, stream>>>(K, V, Kb, VT);
  attn_kernel<<<dim3(256), dim3(512), 0, stream>>>(Q, Kb, VT, O);
}